// Round 1
// baseline (154.581 us; speedup 1.0000x reference)
//
#include <hip/hip_runtime.h>
#include <hip/hip_bf16.h>

// Problem constants (RetrieverBase): q[64][32][128], p[128][180][128] (f32)
// out = concat(term_relevance[64][128][32][180], query_maxsim[64][128][32], relevance[64][128])
#define A_N 64
#define B_N 128
#define Q_N 32
#define D_N 180
#define V_N 128

typedef __attribute__((ext_vector_type(8))) short bf16x8;   // 8 bf16 (4 VGPRs)
typedef __attribute__((ext_vector_type(4))) float f32x4;

__device__ __forceinline__ short f2bf(float f) {
  __hip_bfloat16 h = __float2bfloat16(f);   // RTN; compiler emits v_cvt_pk_bf16_f32 pairs
  return (short)__builtin_bit_cast(unsigned short, h);
}

// Load 8 consecutive f32 (32B) and convert to a bf16x8 MFMA fragment.
__device__ __forceinline__ bf16x8 cvt_frag(const float* __restrict__ src) {
  f32x4 lo = *reinterpret_cast<const f32x4*>(src);
  f32x4 hi = *reinterpret_cast<const f32x4*>(src + 4);
  bf16x8 v;
  v[0] = f2bf(lo[0]); v[1] = f2bf(lo[1]); v[2] = f2bf(lo[2]); v[3] = f2bf(lo[3]);
  v[4] = f2bf(hi[0]); v[5] = f2bf(hi[1]); v[6] = f2bf(hi[2]); v[7] = f2bf(hi[3]);
  return v;
}

// One block per (a,b) pair: C[32 x 180] = q[a] (32x128) * p[b]^T (180x128)^T
// 4 waves; wave w owns n-tiles [3w, 3w+3), m-tiles {0,1}. K=128 -> 4 MFMA steps.
__global__ __launch_bounds__(256) void score_kernel(
    const float* __restrict__ q, const float* __restrict__ p,
    float* __restrict__ out) {
  const int bid  = blockIdx.x;
  const int a    = bid >> 7;          // /128
  const int b    = bid & (B_N - 1);
  const int tid  = threadIdx.x;
  const int wave = tid >> 6;
  const int lane = tid & 63;
  const int l16  = lane & 15;
  const int g    = lane >> 4;         // 0..3 (k-group / row-group)

  const float* __restrict__ qa = q + (size_t)a * Q_N * V_N;
  const float* __restrict__ pb = p + (size_t)b * D_N * V_N;

  f32x4 acc[2][3];
#pragma unroll
  for (int m = 0; m < 2; ++m)
#pragma unroll
    for (int n = 0; n < 3; ++n)
      acc[m][n] = (f32x4){0.f, 0.f, 0.f, 0.f};

  // B-fragment doc column per n-tile (this lane)
  int dcol[3];
#pragma unroll
  for (int n = 0; n < 3; ++n)
    dcol[n] = (wave * 3 + n) * 16 + l16;

#pragma unroll
  for (int kk = 0; kk < 4; ++kk) {
    const int kbase = kk * 32 + g * 8;
    // A fragments: A[row = l16 + 16m][k = kbase..kbase+7]
    bf16x8 afr[2];
#pragma unroll
    for (int m = 0; m < 2; ++m)
      afr[m] = cvt_frag(qa + (size_t)(m * 16 + l16) * V_N + kbase);
    // B fragments: B[k][col = dcol], source row p[b][dcol][kbase..+7]
    bf16x8 bfr[3];
#pragma unroll
    for (int n = 0; n < 3; ++n) {
      const int dc = dcol[n] < D_N ? dcol[n] : (D_N - 1);  // clamp: padded cols read row 179 (never stored)
      bfr[n] = cvt_frag(pb + (size_t)dc * V_N + kbase);
    }
#pragma unroll
    for (int m = 0; m < 2; ++m)
#pragma unroll
      for (int n = 0; n < 3; ++n)
        acc[m][n] = __builtin_amdgcn_mfma_f32_16x16x32_bf16(afr[m], bfr[n], acc[m][n], 0, 0, 0);
  }

  // ---- store term_relevance + per-lane running max over doc tokens ----
  // C/D layout (m89-verified): col = lane&15, row = (lane>>4)*4 + reg
  const size_t outbase = ((size_t)a * B_N + b) * (size_t)(Q_N * D_N);
  float lmax[2][4];
#pragma unroll
  for (int m = 0; m < 2; ++m)
#pragma unroll
    for (int r = 0; r < 4; ++r)
      lmax[m][r] = -INFINITY;

#pragma unroll
  for (int m = 0; m < 2; ++m) {
    const int row0 = m * 16 + g * 4;
#pragma unroll
    for (int n = 0; n < 3; ++n) {
      const int d = dcol[n];
      if (d < D_N) {
#pragma unroll
        for (int r = 0; r < 4; ++r) {
          const float v = acc[m][n][r];
          out[outbase + (size_t)(row0 + r) * D_N + d] = v;
          lmax[m][r] = fmaxf(lmax[m][r], v);
        }
      }
    }
  }

  // max across the 16 lanes of a column group (same rows, different d)
#pragma unroll
  for (int m = 0; m < 2; ++m)
#pragma unroll
    for (int r = 0; r < 4; ++r) {
      float v = lmax[m][r];
#pragma unroll
      for (int s = 1; s <= 8; s <<= 1)
        v = fmaxf(v, __shfl_xor(v, s, 64));
      lmax[m][r] = v;
    }

  // cross-wave max via tiny LDS: each wave contributes 32 row-maxes
  __shared__ float smax[4][Q_N];
  if (l16 == 0) {
#pragma unroll
    for (int m = 0; m < 2; ++m)
#pragma unroll
      for (int r = 0; r < 4; ++r)
        smax[wave][m * 16 + g * 4 + r] = lmax[m][r];
  }
  __syncthreads();

  if (tid < Q_N) {
    const float v = fmaxf(fmaxf(smax[0][tid], smax[1][tid]),
                          fmaxf(smax[2][tid], smax[3][tid]));
    const size_t TERM_SZ = (size_t)A_N * B_N * Q_N * D_N;
    out[TERM_SZ + ((size_t)a * B_N + b) * Q_N + tid] = v;   // query_maxsim
    float ssum = v;
#pragma unroll
    for (int s = 1; s <= 16; s <<= 1)
      ssum += __shfl_xor(ssum, s, 64);
    if (tid == 0)
      out[TERM_SZ + (size_t)A_N * B_N * Q_N + (size_t)a * B_N + b] = ssum;  // relevance
  }
}

extern "C" void kernel_launch(void* const* d_in, const int* in_sizes, int n_in,
                              void* d_out, int out_size, void* d_ws, size_t ws_size,
                              hipStream_t stream) {
  const float* q = (const float*)d_in[0];
  const float* p = (const float*)d_in[1];
  float* out = (float*)d_out;
  dim3 grid(A_N * B_N);   // one block per (a,b) pair
  dim3 block(256);
  hipLaunchKernelGGL(score_kernel, grid, block, 0, stream, q, p, out);
}

// Round 2
// 153.498 us; speedup vs baseline: 1.0071x; 1.0071x over previous
//
#include <hip/hip_runtime.h>
#include <hip/hip_bf16.h>

// RetrieverBase: q[64][32][128] f32, p[128][180][128] f32
// out = concat(term_relevance[64][128][32][180], query_maxsim[64][128][32], relevance[64][128])
#define A_N 64
#define B_N 128
#define Q_N 32
#define D_N 180
#define V_N 128

typedef __attribute__((ext_vector_type(8))) short bf16x8;   // 8 bf16 (4 VGPRs)
typedef __attribute__((ext_vector_type(4))) float f32x4;

__device__ __forceinline__ short f2bf(float f) {
  __hip_bfloat16 h = __float2bfloat16(f);
  return (short)__builtin_bit_cast(unsigned short, h);
}

// Load 8 consecutive f32 (32B) and convert to a bf16x8 MFMA fragment.
__device__ __forceinline__ bf16x8 cvt_frag(const float* __restrict__ src) {
  f32x4 lo = *reinterpret_cast<const f32x4*>(src);
  f32x4 hi = *reinterpret_cast<const f32x4*>(src + 4);
  bf16x8 v;
  v[0] = f2bf(lo[0]); v[1] = f2bf(lo[1]); v[2] = f2bf(lo[2]); v[3] = f2bf(lo[3]);
  v[4] = f2bf(hi[0]); v[5] = f2bf(hi[1]); v[6] = f2bf(hi[2]); v[7] = f2bf(hi[3]);
  return v;
}

// One block per (a,b). SWAPPED operands: C[d][q] = p[b] (180x128) * q[a]^T.
// C/D layout: col = lane&15 = q-col, row = (lane>>4)*4 + reg = d-row
//  -> each lane's 4 acc regs are 4 CONSECUTIVE d for one q => dwordx4 stores.
// 12 d-tiles of 16 (192, tail clamped); wave w owns d-tiles {w, w+4, w+8}.
__global__ __launch_bounds__(256) void score_kernel(
    const float* __restrict__ q, const float* __restrict__ p,
    float* __restrict__ out) {
  const int bid  = blockIdx.x;
  const int a    = bid >> 7;
  const int b    = bid & (B_N - 1);
  const int tid  = threadIdx.x;
  const int wave = tid >> 6;
  const int lane = tid & 63;
  const int l16  = lane & 15;
  const int g    = lane >> 4;   // 0..3

  const float* __restrict__ qa = q + (size_t)a * Q_N * V_N;
  const float* __restrict__ pb = p + (size_t)b * D_N * V_N;

  // Hoist q as B-fragments: B[k][col=q] -> lane reads q[l16 + 16*qt][g*8 + kk*32 ..+7]
  bf16x8 qf[2][4];
#pragma unroll
  for (int qt = 0; qt < 2; ++qt)
#pragma unroll
    for (int kk = 0; kk < 4; ++kk)
      qf[qt][kk] = cvt_frag(qa + (size_t)(qt * 16 + l16) * V_N + kk * 32 + g * 8);

  float qmax[2] = {-INFINITY, -INFINITY};  // per-lane max over owned d, q = qt*16+l16
  const size_t outbase = ((size_t)a * B_N + b) * (size_t)(Q_N * D_N);

#pragma unroll
  for (int i = 0; i < 3; ++i) {
    const int dt = wave + i * 4;           // d-tile index 0..11
    // A-fragment from p: A[row=d][k]; lane reads p-row (dt*16 + l16), clamped for tail tile
    const int drow = dt * 16 + l16;
    const int dr   = drow < D_N ? drow : (D_N - 1);
    bf16x8 pf[4];
#pragma unroll
    for (int kk = 0; kk < 4; ++kk)
      pf[kk] = cvt_frag(pb + (size_t)dr * V_N + kk * 32 + g * 8);

    f32x4 acc[2] = {(f32x4){0.f,0.f,0.f,0.f}, (f32x4){0.f,0.f,0.f,0.f}};
#pragma unroll
    for (int kk = 0; kk < 4; ++kk)
#pragma unroll
      for (int qt = 0; qt < 2; ++qt)
        acc[qt] = __builtin_amdgcn_mfma_f32_16x16x32_bf16(pf[kk], qf[qt][kk], acc[qt], 0, 0, 0);

    // lane holds C[d0..d0+3][qq]; tail-tile clamp duplicates d=179 values -> max-safe
    const int d0 = dt * 16 + g * 4;
#pragma unroll
    for (int qt = 0; qt < 2; ++qt) {
      const int qq = qt * 16 + l16;
      qmax[qt] = fmaxf(qmax[qt],
                       fmaxf(fmaxf(acc[qt][0], acc[qt][1]),
                             fmaxf(acc[qt][2], acc[qt][3])));
      if (d0 < D_N) {   // only invalid for dt==11, g>0
        f32x4* dst = reinterpret_cast<f32x4*>(out + outbase + (size_t)qq * D_N + d0);
        __builtin_nontemporal_store(acc[qt], dst);
      }
    }
  }

  // reduce max across the 4 g-groups (same q, different d sub-rows)
#pragma unroll
  for (int qt = 0; qt < 2; ++qt) {
    float v = qmax[qt];
    v = fmaxf(v, __shfl_xor(v, 16, 64));
    v = fmaxf(v, __shfl_xor(v, 32, 64));
    qmax[qt] = v;
  }

  // cross-wave max
  __shared__ float smax[4][Q_N];
  if (lane < 16) {
#pragma unroll
    for (int qt = 0; qt < 2; ++qt)
      smax[wave][qt * 16 + lane] = qmax[qt];
  }
  __syncthreads();

  if (tid < Q_N) {
    const float v = fmaxf(fmaxf(smax[0][tid], smax[1][tid]),
                          fmaxf(smax[2][tid], smax[3][tid]));
    const size_t TERM_SZ = (size_t)A_N * B_N * Q_N * D_N;
    out[TERM_SZ + ((size_t)a * B_N + b) * Q_N + tid] = v;   // query_maxsim
    float ssum = v;
#pragma unroll
    for (int s = 1; s <= 16; s <<= 1)
      ssum += __shfl_xor(ssum, s, 64);
    if (tid == 0)
      out[TERM_SZ + (size_t)A_N * B_N * Q_N + (size_t)a * B_N + b] = ssum;  // relevance
  }
}

extern "C" void kernel_launch(void* const* d_in, const int* in_sizes, int n_in,
                              void* d_out, int out_size, void* d_ws, size_t ws_size,
                              hipStream_t stream) {
  const float* q = (const float*)d_in[0];
  const float* p = (const float*)d_in[1];
  float* out = (float*)d_out;
  dim3 grid(A_N * B_N);
  dim3 block(256);
  hipLaunchKernelGGL(score_kernel, grid, block, 0, stream, q, p, out);
}

// Round 3
// 118.805 us; speedup vs baseline: 1.3011x; 1.2920x over previous
//
#include <hip/hip_runtime.h>
#include <hip/hip_bf16.h>

// RetrieverBase: q[64][32][128] f32, p[128][180][128] f32
// out = concat(term_relevance[64][128][32][180], query_maxsim[64][128][32], relevance[64][128])
#define A_N 64
#define B_N 128
#define Q_N 32
#define D_N 180
#define V_N 128

typedef __attribute__((ext_vector_type(8))) short bf16x8;   // 8 bf16 (4 VGPRs)
typedef __attribute__((ext_vector_type(4))) float f32x4;

__device__ __forceinline__ short f2bf(float f) {
  __hip_bfloat16 h = __float2bfloat16(f);
  return (short)__builtin_bit_cast(unsigned short, h);
}

__device__ __forceinline__ bf16x8 pack8(const f32x4& lo, const f32x4& hi) {
  bf16x8 v;
  v[0] = f2bf(lo[0]); v[1] = f2bf(lo[1]); v[2] = f2bf(lo[2]); v[3] = f2bf(lo[3]);
  v[4] = f2bf(hi[0]); v[5] = f2bf(hi[1]); v[6] = f2bf(hi[2]); v[7] = f2bf(hi[3]);
  return v;
}

// Grid 2048 = 32 b-groups x 64 a. Block = 4 waves; wave w owns b = bg*4 + w.
// Each wave computes the FULL C[32x180] = p[b] * q[a]^T for its (a,b):
// no LDS, no __syncthreads, maxsim/relevance reduced in-register.
// C/D layout: col = lane&15 = q, row = (lane>>4)*4 + reg = d (4 consecutive d
// per lane -> dwordx4 stores). 12 d-tiles of 16 (tail clamps p-row to 179,
// duplicates are max-safe and never stored).
__global__ __launch_bounds__(256) void score_kernel(
    const float* __restrict__ q, const float* __restrict__ p,
    float* __restrict__ out) {
  const int bid  = blockIdx.x;
  const int a    = bid & 63;          // a fast -> 64 same-bg blocks co-dispatched
  const int bg   = bid >> 6;          // 0..31
  const int tid  = threadIdx.x;
  const int wave = tid >> 6;
  const int lane = tid & 63;
  const int l16  = lane & 15;
  const int g    = lane >> 4;         // 0..3
  const int b    = bg * 4 + wave;

  const float* __restrict__ qa = q + (size_t)a * Q_N * V_N;
  const float* __restrict__ pb = p + (size_t)b * D_N * V_N;

  // q as B-fragments: B[k][col=q]; lane reads q[qt*16+l16][kk*32+g*8 ..+7]
  bf16x8 qf[2][4];
#pragma unroll
  for (int qt = 0; qt < 2; ++qt)
#pragma unroll
    for (int kk = 0; kk < 4; ++kk) {
      const float* s = qa + (size_t)(qt * 16 + l16) * V_N + kk * 32 + g * 8;
      qf[qt][kk] = pack8(*reinterpret_cast<const f32x4*>(s),
                         *reinterpret_cast<const f32x4*>(s + 4));
    }

  // raw-f32 double buffer for p-tile prefetch (8 x f32x4 per tile)
  f32x4 bufA[8], bufB[8];
  const float* pl = pb + g * 8;   // lane's column base within a p-row

#define LOADRAW(dst, dt)                                                     \
  {                                                                          \
    const int drow = (dt) * 16 + l16;                                        \
    const int dr   = drow < D_N ? drow : (D_N - 1);                          \
    const float* s = pl + (size_t)dr * V_N;                                  \
    _Pragma("unroll")                                                        \
    for (int kk = 0; kk < 4; ++kk) {                                         \
      dst[2 * kk]     = *reinterpret_cast<const f32x4*>(s + kk * 32);        \
      dst[2 * kk + 1] = *reinterpret_cast<const f32x4*>(s + kk * 32 + 4);    \
    }                                                                        \
  }

  LOADRAW(bufA, 0);

  float qmax[2] = {-INFINITY, -INFINITY};
  const size_t outbase = ((size_t)a * B_N + b) * (size_t)(Q_N * D_N);

#pragma unroll
  for (int dt = 0; dt < 12; ++dt) {
    f32x4* cur = (dt & 1) ? bufB : bufA;   // dt is compile-time (full unroll)
    f32x4* nxt = (dt & 1) ? bufA : bufB;
    if (dt < 11) LOADRAW(nxt, dt + 1);     // next tile's 8 loads in flight

    bf16x8 pf[4];
#pragma unroll
    for (int kk = 0; kk < 4; ++kk)
      pf[kk] = pack8(cur[2 * kk], cur[2 * kk + 1]);

    f32x4 acc0 = (f32x4){0.f, 0.f, 0.f, 0.f};
    f32x4 acc1 = (f32x4){0.f, 0.f, 0.f, 0.f};
#pragma unroll
    for (int kk = 0; kk < 4; ++kk) {
      acc0 = __builtin_amdgcn_mfma_f32_16x16x32_bf16(pf[kk], qf[0][kk], acc0, 0, 0, 0);
      acc1 = __builtin_amdgcn_mfma_f32_16x16x32_bf16(pf[kk], qf[1][kk], acc1, 0, 0, 0);
    }

    const int d0 = dt * 16 + g * 4;
    qmax[0] = fmaxf(qmax[0], fmaxf(fmaxf(acc0[0], acc0[1]), fmaxf(acc0[2], acc0[3])));
    qmax[1] = fmaxf(qmax[1], fmaxf(fmaxf(acc1[0], acc1[1]), fmaxf(acc1[2], acc1[3])));
    if (d0 < D_N) {   // only dt==11, g>0 masked
      *reinterpret_cast<f32x4*>(out + outbase + (size_t)l16 * D_N + d0) = acc0;
      *reinterpret_cast<f32x4*>(out + outbase + (size_t)(16 + l16) * D_N + d0) = acc1;
    }
  }
#undef LOADRAW

  // reduce max across the 4 g-groups (different d sub-rows, same q)
#pragma unroll
  for (int qt = 0; qt < 2; ++qt) {
    float v = qmax[qt];
    v = fmaxf(v, __shfl_xor(v, 16, 64));
    v = fmaxf(v, __shfl_xor(v, 32, 64));
    qmax[qt] = v;
  }

  const size_t TERM_SZ = (size_t)A_N * B_N * Q_N * D_N;
  if (lane < 16) {   // write maxsim for q = qt*16 + lane
    float* ms = out + TERM_SZ + ((size_t)a * B_N + b) * Q_N;
    ms[lane]      = qmax[0];
    ms[16 + lane] = qmax[1];
  }

  // relevance = sum over 32 q of maxsim
  float s = qmax[0] + qmax[1];
  s += __shfl_xor(s, 1, 64);
  s += __shfl_xor(s, 2, 64);
  s += __shfl_xor(s, 4, 64);
  s += __shfl_xor(s, 8, 64);
  if (lane == 0)
    out[TERM_SZ + (size_t)A_N * B_N * Q_N + (size_t)a * B_N + b] = s;
}

extern "C" void kernel_launch(void* const* d_in, const int* in_sizes, int n_in,
                              void* d_out, int out_size, void* d_ws, size_t ws_size,
                              hipStream_t stream) {
  const float* q = (const float*)d_in[0];
  const float* p = (const float*)d_in[1];
  float* out = (float*)d_out;
  dim3 grid(2048);   // 32 b-groups x 64 a
  dim3 block(256);   // 4 waves, one b per wave
  hipLaunchKernelGGL(score_kernel, grid, block, 0, stream, q, p, out);
}